// Round 1
// baseline (1260.044 us; speedup 1.0000x reference)
//
#include <hip/hip_runtime.h>
#include <math.h>

// Problem constants
#define BB   8
#define TT   16
#define HH   64
#define WW   64
#define CINc 32
#define FFc  32
#define GG   128    // 4*F gate channels
#define TH   8
#define TW   8
#define INS  68     // LDS stride per patch position: 64 ch + 4 pad (bank-conflict + 16B align)
#define HSZ  (BB*HH*WW*FFc)   // elements per state buffer (1,048,576 floats = 4 MB)

// One timestep: fused conv(x_t,Wx)+conv(h_prev,Wh)+b -> gates -> LSTM update -> BN -> out
// Block: 8x8 pixel tile of one batch image, 256 threads.
// Thread tile: 4 pixels x 8 gate channels (register accs).
__global__ __launch_bounds__(256, 2)
void convlstm_step(const float* __restrict__ x,      // [B,T,H,W,CIN]
                   const float* __restrict__ Wx,     // [3,3,CIN,128]
                   const float* __restrict__ Wh,     // [3,3,F,128]
                   const float* __restrict__ bias,   // [128]
                   const float* __restrict__ gamma_, // [32]
                   const float* __restrict__ beta_,  // [32]
                   const float* __restrict__ mmean,  // [32]
                   const float* __restrict__ mvar,   // [32]
                   const float* __restrict__ hprev,  // [B,H,W,F]
                   float* __restrict__ hnext,        // [B,H,W,F]
                   float* __restrict__ cstate,       // [B,H,W,F]
                   float* __restrict__ out,          // [B,T,H,W,F]
                   int t)
{
    __shared__ float ins[10*10*INS];   // 27.2 KB: x||h patch, zero-padded halo
    __shared__ float wsh[64*GG];       // 32 KB: per-(ky,kx) weight slice; reused as gate buffer

    const int tid = threadIdx.x;
    const int tx  = blockIdx.x;   // W/8
    const int ty  = blockIdx.y;   // H/8
    const int b   = blockIdx.z;   // B

    // ---- stage input patch: 10x10 positions, 32 x-ch + 32 h-ch, float4 chunks ----
    const float* xt = x     + (((size_t)b*TT + t)*HH*WW)*CINc;
    const float* hp = hprev + ((size_t)b*HH*WW)*FFc;
    for (int i = tid; i < 100*8; i += 256) {
        const int pos = i >> 3;
        const int ch4 = (i & 7) * 4;
        const int row = pos / 10;
        const int col = pos - row*10;
        const int gy = ty*TH + row - 1;
        const int gx = tx*TW + col - 1;
        float4 vx = make_float4(0.f,0.f,0.f,0.f);
        float4 vh = vx;
        if ((unsigned)gy < HH && (unsigned)gx < WW) {
            const size_t pix = (size_t)(gy*WW + gx);
            vx = *(const float4*)(xt + pix*CINc + ch4);
            vh = *(const float4*)(hp + pix*FFc  + ch4);
        }
        *(float4*)&ins[(row*10+col)*INS + ch4]      = vx;
        *(float4*)&ins[(row*10+col)*INS + 32 + ch4] = vh;
    }

    // thread tile mapping
    const int cgrp = tid & 15;     // channel group: 8 gate channels
    const int pg   = tid >> 4;     // pixel group: 4 pixels
    const int cb   = cgrp * 8;

    // acc init = bias
    float acc[4][8];
    #pragma unroll
    for (int j = 0; j < 8; ++j) {
        const float bj = bias[cb + j];
        acc[0][j] = bj; acc[1][j] = bj; acc[2][j] = bj; acc[3][j] = bj;
    }

    // per-pixel LDS base offsets (output pixel (py,px) -> patch base (py,px))
    int pbase[4];
    #pragma unroll
    for (int p = 0; p < 4; ++p) {
        const int pix = pg*4 + p;
        pbase[p] = ((pix >> 3)*10 + (pix & 7)) * INS;
    }

    // ---- 3x3 loop: stage weight slice [64ci][128co] then FMA over 64 ci ----
    for (int kk = 0; kk < 9; ++kk) {
        __syncthreads();   // protect wsh (prev compute / gate reuse) and ins stores
        const float* wxk = Wx + kk*CINc*GG;
        const float* whk = Wh + kk*FFc*GG;
        for (int i = tid; i < 64*32; i += 256) {
            const int ci = i >> 5;
            const int c4 = (i & 31) * 4;
            float4 w;
            if (ci < 32) w = *(const float4*)(wxk + ci*GG + c4);
            else         w = *(const float4*)(whk + (ci-32)*GG + c4);
            *(float4*)&wsh[ci*GG + c4] = w;
        }
        __syncthreads();

        const int ky = kk / 3;
        const int kx = kk - ky*3;
        const float* insk = &ins[(ky*10 + kx)*INS];

        #pragma unroll 4
        for (int ci = 0; ci < 64; ++ci) {
            const float iv0 = insk[pbase[0] + ci];
            const float iv1 = insk[pbase[1] + ci];
            const float iv2 = insk[pbase[2] + ci];
            const float iv3 = insk[pbase[3] + ci];
            const float4 wa = *(const float4*)&wsh[ci*GG + cb];
            const float4 wb = *(const float4*)&wsh[ci*GG + cb + 4];
            const float wv[8] = {wa.x,wa.y,wa.z,wa.w,wb.x,wb.y,wb.z,wb.w};
            const float iv[4] = {iv0,iv1,iv2,iv3};
            #pragma unroll
            for (int p = 0; p < 4; ++p)
                #pragma unroll
                for (int j = 0; j < 8; ++j)
                    acc[p][j] += iv[p] * wv[j];
        }
    }

    // ---- regroup gates via LDS (reuse wsh as g[64 pixels][128 ch]) ----
    __syncthreads();
    #pragma unroll
    for (int p = 0; p < 4; ++p) {
        *(float4*)&wsh[(pg*4+p)*GG + cb]     = make_float4(acc[p][0],acc[p][1],acc[p][2],acc[p][3]);
        *(float4*)&wsh[(pg*4+p)*GG + cb + 4] = make_float4(acc[p][4],acc[p][5],acc[p][6],acc[p][7]);
    }
    __syncthreads();

    // ---- LSTM pointwise + BN; thread handles 8 (pixel, f) pairs ----
    const int f    = tid & 31;
    const int psub = tid >> 5;   // 0..7
    const float inv  = gamma_[f] * rsqrtf(mvar[f] + 1e-3f);
    const float bnb  = beta_[f] - mmean[f] * inv;
    float* hq = hnext  + ((size_t)b*HH*WW)*FFc;
    float* cq = cstate + ((size_t)b*HH*WW)*FFc;
    float* oq = out + (((size_t)b*TT + t)*HH*WW)*FFc;

    #pragma unroll
    for (int pp = 0; pp < 8; ++pp) {
        const int pix = psub*8 + pp;
        const int py = pix >> 3, px = pix & 7;
        const int gy = ty*TH + py, gx = tx*TW + px;
        const size_t gidx = ((size_t)(gy*WW + gx))*FFc + f;
        float gi = wsh[pix*GG + f];
        float gf = wsh[pix*GG + 32 + f];
        float gc = wsh[pix*GG + 64 + f];
        float go = wsh[pix*GG + 96 + f];
        gi = fminf(fmaxf(0.2f*gi + 0.5f, 0.f), 1.f);
        gf = fminf(fmaxf(0.2f*gf + 0.5f, 0.f), 1.f);
        go = fminf(fmaxf(0.2f*go + 0.5f, 0.f), 1.f);
        const float c_old = cq[gidx];
        const float c_new = gf * c_old + gi * tanhf(gc);
        const float h_new = go * tanhf(c_new);
        cq[gidx] = c_new;
        hq[gidx] = h_new;
        oq[gidx] = h_new * inv + bnb;
    }
}

extern "C" void kernel_launch(void* const* d_in, const int* in_sizes, int n_in,
                              void* d_out, int out_size, void* d_ws, size_t ws_size,
                              hipStream_t stream)
{
    const float* x      = (const float*)d_in[0];
    const float* Wx     = (const float*)d_in[1];
    const float* Wh     = (const float*)d_in[2];
    const float* bias   = (const float*)d_in[3];
    const float* gamma_ = (const float*)d_in[4];
    const float* beta_  = (const float*)d_in[5];
    const float* mmean  = (const float*)d_in[6];
    const float* mvar   = (const float*)d_in[7];
    float* out = (float*)d_out;

    // workspace: [h0 (4MB)][c (4MB)][h1 (4MB)]; zero h0 and c
    float* h0 = (float*)d_ws;
    float* cs = h0 + HSZ;
    float* h1 = cs + HSZ;
    hipMemsetAsync(d_ws, 0, (size_t)2*HSZ*sizeof(float), stream);

    dim3 grid(WW/TW, HH/TH, BB);   // (8,8,8) = 512 blocks, 2 per CU
    float* hprev = h0;
    float* hnext = h1;
    for (int t = 0; t < TT; ++t) {
        convlstm_step<<<grid, 256, 0, stream>>>(x, Wx, Wh, bias, gamma_, beta_,
                                                mmean, mvar, hprev, hnext, cs, out, t);
        float* tmp = hprev; hprev = hnext; hnext = tmp;
    }
}

// Round 2
// 469.744 us; speedup vs baseline: 2.6824x; 2.6824x over previous
//
#include <hip/hip_runtime.h>
#include <math.h>

// Problem constants
#define BB   8
#define TT   16
#define HH   64
#define WW   64
#define CINc 32
#define FFc  32
#define GG   128          // 4*F gate channels
#define KK   576          // 9 taps * 64 ci (32 x-ch || 32 h-ch)
#define PSTR 72           // LDS fp16 stride per patch pos / weight row (64 + 8 pad -> 144B, 16B aligned, ~2-way banks)

typedef _Float16 half8 __attribute__((ext_vector_type(8)));
typedef float    f32x4 __attribute__((ext_vector_type(4)));

__device__ __forceinline__ float fast_tanh(float v) {
    // tanh(x) = 1 - 2/(e^{2x}+1); exact limits at +/-inf, ~1e-6 rel err
    float e = __expf(2.f * v);
    return 1.f - 2.f / (e + 1.f);
}
__device__ __forceinline__ float hsig(float v) {
    return fminf(fmaxf(0.2f * v + 0.5f, 0.f), 1.f);
}

// Pack weights: Wt[n][k], k = tap*64 + ci; ci<32 from Wx[tap][ci][n], else Wh[tap][ci-32][n]
__global__ void prep_w(const float* __restrict__ Wx, const float* __restrict__ Wh,
                       _Float16* __restrict__ Wt) {
    const int k = blockIdx.x;      // 0..575
    const int n = threadIdx.x;     // 0..127
    const int tap = k >> 6, ci = k & 63;
    const float v = (ci < 32) ? Wx[(tap * 32 + ci) * GG + n]
                              : Wh[(tap * 32 + (ci - 32)) * GG + n];
    Wt[n * KK + k] = (_Float16)v;
}

// One timestep: fused conv(x_t,Wx)+conv(h,Wh)+bias -> gates -> LSTM -> BN -> out
// Block: 8 rows x 16 cols pixel tile (128 px) x 128 gates, 256 threads (4 waves).
// Wave w: pixel rows {2w, 2w+1} x all 128 gates -> 2x8 mfma_f32_16x16x32_f16 acc tiles.
__global__ __launch_bounds__(256, 1)
void convlstm_step(const float* __restrict__ x,       // [B,T,H,W,32] fp32
                   const _Float16* __restrict__ Wt,   // [128][576] fp16
                   const float* __restrict__ bias,    // [128]
                   const float* __restrict__ gamma_,  // [32]
                   const float* __restrict__ beta_,   // [32]
                   const float* __restrict__ mmean,   // [32]
                   const float* __restrict__ mvar,    // [32]
                   const _Float16* __restrict__ hprev,// [B,H,W,32] fp16
                   _Float16* __restrict__ hnext,      // [B,H,W,32] fp16
                   float* __restrict__ cstate,        // [B,H,W,32] fp32
                   float* __restrict__ out,           // [B,T,H,W,32] fp32
                   int t)
{
    __shared__ _Float16 patch[10 * 18 * PSTR];   // 25.9 KB: x||h patch, halo zero-padded
    __shared__ _Float16 wbuf[2][GG * PSTR];      // 36.9 KB: double-buffered per-tap weights

    const int tid  = threadIdx.x;
    const int lane = tid & 63;
    const int w    = tid >> 6;       // wave 0..3
    const int l15  = lane & 15;
    const int quad = lane >> 4;
    const int px0  = blockIdx.x * 16;  // 0..48
    const int py0  = blockIdx.y * 8;   // 0..56
    const int b    = blockIdx.z;

    const float*     xt = x     + (((size_t)b * TT + t) * HH * WW) * CINc;
    const _Float16*  hp = hprev + ((size_t)b * HH * WW) * FFc;

    // ---- patch staging: 180 pos x 8 slots of 8 channels (slots 0-3 = x fp32->fp16, 4-7 = h fp16) ----
    for (int i = tid; i < 180 * 8; i += 256) {
        const int pos  = i >> 3;
        const int slot = i & 7;
        const int row  = pos / 18;
        const int col  = pos - row * 18;
        const int gy = py0 + row - 1;
        const int gx = px0 + col - 1;
        const bool ok = ((unsigned)gy < HH) && ((unsigned)gx < WW);
        half8 hv = {0, 0, 0, 0, 0, 0, 0, 0};
        if (slot < 4) {
            if (ok) {
                const float* s = xt + ((size_t)(gy * WW + gx)) * CINc + slot * 8;
                const float4 v0 = *(const float4*)s;
                const float4 v1 = *(const float4*)(s + 4);
                hv = (half8){(_Float16)v0.x, (_Float16)v0.y, (_Float16)v0.z, (_Float16)v0.w,
                             (_Float16)v1.x, (_Float16)v1.y, (_Float16)v1.z, (_Float16)v1.w};
            }
        } else {
            if (ok) hv = *(const half8*)(hp + ((size_t)(gy * WW + gx)) * FFc + (slot - 4) * 8);
        }
        *(half8*)&patch[pos * PSTR + slot * 8] = hv;   // x at ci 0..31, h at ci 32..63
    }

    // ---- stage tap-0 weights ----
    #pragma unroll
    for (int i = 0; i < 4; ++i) {
        const int c = tid + i * 256;          // 1024 chunks of 16B
        const int n = c >> 3, sub = c & 7;
        *(uint4*)&wbuf[0][n * PSTR + sub * 8] = *(const uint4*)(Wt + (size_t)n * KK + sub * 8);
    }
    __syncthreads();

    f32x4 acc[2][8];
    #pragma unroll
    for (int mt = 0; mt < 2; ++mt)
        #pragma unroll
        for (int nt = 0; nt < 8; ++nt)
            acc[mt][nt] = (f32x4){0.f, 0.f, 0.f, 0.f};

    // ---- K loop: 9 taps x 2 ksteps of K=32 ----
    for (int tap = 0; tap < 9; ++tap) {
        const int buf = tap & 1;
        uint4 pre[4];
        if (tap < 8) {   // prefetch next tap's weights into registers
            const _Float16* wsrc = Wt + (tap + 1) * 64;
            #pragma unroll
            for (int i = 0; i < 4; ++i) {
                const int c = tid + i * 256;
                const int n = c >> 3, sub = c & 7;
                pre[i] = *(const uint4*)(wsrc + (size_t)n * KK + sub * 8);
            }
        }
        const int ky = tap / 3;
        const int kx = tap - ky * 3;
        const int acol = l15 + kx;

        #pragma unroll
        for (int hk = 0; hk < 2; ++hk) {
            const int ci0 = hk * 32 + quad * 8;
            const half8 a0 = *(const half8*)&patch[((2 * w + 0 + ky) * 18 + acol) * PSTR + ci0];
            const half8 a1 = *(const half8*)&patch[((2 * w + 1 + ky) * 18 + acol) * PSTR + ci0];
            #pragma unroll
            for (int nt = 0; nt < 8; ++nt) {
                const half8 bb = *(const half8*)&wbuf[buf][(nt * 16 + l15) * PSTR + ci0];
                acc[0][nt] = __builtin_amdgcn_mfma_f32_16x16x32_f16(a0, bb, acc[0][nt], 0, 0, 0);
                acc[1][nt] = __builtin_amdgcn_mfma_f32_16x16x32_f16(a1, bb, acc[1][nt], 0, 0, 0);
            }
        }
        if (tap < 8) {
            #pragma unroll
            for (int i = 0; i < 4; ++i) {
                const int c = tid + i * 256;
                const int n = c >> 3, sub = c & 7;
                *(uint4*)&wbuf[1 - buf][n * PSTR + sub * 8] = pre[i];
            }
        }
        __syncthreads();
    }

    // ---- epilogue: lane holds i/f/c/o for features {l15, l15+16} x 8 pixels. No LDS needed. ----
    const int f1 = l15, f2 = l15 + 16;
    const float inv1 = gamma_[f1] * rsqrtf(mvar[f1] + 1e-3f);
    const float inv2 = gamma_[f2] * rsqrtf(mvar[f2] + 1e-3f);
    const float bnb1 = beta_[f1] - mmean[f1] * inv1;
    const float bnb2 = beta_[f2] - mmean[f2] * inv2;
    float bi1[4], bi2[4];
    #pragma unroll
    for (int g = 0; g < 4; ++g) { bi1[g] = bias[g * 32 + f1]; bi2[g] = bias[g * 32 + f2]; }

    const size_t base_b = (size_t)b * HH * WW * FFc;
    float* oq = out + (((size_t)b * TT + t) * HH * WW) * FFc;

    #pragma unroll
    for (int mt = 0; mt < 2; ++mt) {
        const int gy = py0 + 2 * w + mt;
        #pragma unroll
        for (int r = 0; r < 4; ++r) {
            const int gx = px0 + quad * 4 + r;
            const size_t pix = (size_t)(gy * WW + gx) * FFc;
            // feature f1 (even nt), f2 (odd nt); gate order i,f,c,o = nt/2
            const float gi1 = acc[mt][0][r] + bi1[0], gi2 = acc[mt][1][r] + bi2[0];
            const float gf1 = acc[mt][2][r] + bi1[1], gf2 = acc[mt][3][r] + bi2[1];
            const float gc1 = acc[mt][4][r] + bi1[2], gc2 = acc[mt][5][r] + bi2[2];
            const float go1 = acc[mt][6][r] + bi1[3], go2 = acc[mt][7][r] + bi2[3];

            const float c1o = cstate[base_b + pix + f1];
            const float c2o = cstate[base_b + pix + f2];
            const float c1 = hsig(gf1) * c1o + hsig(gi1) * fast_tanh(gc1);
            const float c2 = hsig(gf2) * c2o + hsig(gi2) * fast_tanh(gc2);
            const float h1 = hsig(go1) * fast_tanh(c1);
            const float h2 = hsig(go2) * fast_tanh(c2);
            cstate[base_b + pix + f1] = c1;
            cstate[base_b + pix + f2] = c2;
            hnext[base_b + pix + f1] = (_Float16)h1;
            hnext[base_b + pix + f2] = (_Float16)h2;
            oq[pix + f1] = h1 * inv1 + bnb1;
            oq[pix + f2] = h2 * inv2 + bnb2;
        }
    }
}

extern "C" void kernel_launch(void* const* d_in, const int* in_sizes, int n_in,
                              void* d_out, int out_size, void* d_ws, size_t ws_size,
                              hipStream_t stream)
{
    const float* x      = (const float*)d_in[0];
    const float* Wx     = (const float*)d_in[1];
    const float* Wh     = (const float*)d_in[2];
    const float* bias   = (const float*)d_in[3];
    const float* gamma_ = (const float*)d_in[4];
    const float* beta_  = (const float*)d_in[5];
    const float* mmean  = (const float*)d_in[6];
    const float* mvar   = (const float*)d_in[7];
    float* out = (float*)d_out;

    // ws layout: [h0 fp16 2MB][c fp32 4MB][h1 fp16 2MB][Wt fp16 147KB]  (~8.4 MB)
    char* wsb = (char*)d_ws;
    _Float16* h0 = (_Float16*)wsb;
    float*    cs = (float*)(wsb + (2 << 20));
    _Float16* h1 = (_Float16*)(wsb + (6 << 20));
    _Float16* Wt = (_Float16*)(wsb + (8 << 20));

    hipMemsetAsync(d_ws, 0, (size_t)6 << 20, stream);   // zero h0 + c
    prep_w<<<dim3(KK), dim3(GG), 0, stream>>>(Wx, Wh, Wt);

    dim3 grid(WW / 16, HH / 8, BB);   // (4,8,8) = 256 blocks, 1 per CU
    _Float16* hprev = h0;
    _Float16* hnext = h1;
    for (int t = 0; t < TT; ++t) {
        convlstm_step<<<grid, 256, 0, stream>>>(x, Wt, bias, gamma_, beta_,
                                                mmean, mvar, hprev, hnext, cs, out, t);
        _Float16* tmp = hprev; hprev = hnext; hnext = tmp;
    }
}